// Round 1
// baseline (2280.451 us; speedup 1.0000x reference)
//
#include <hip/hip_runtime.h>

#define N0v 614400
#define N1v 40960
#define BATCHv 4096
#define F0v 15
#define F1v 10

static __device__ __forceinline__ float flog1p(float v) { return __logf(v + 1.0f); }
static __device__ __forceinline__ float sigf(float v) { return 1.0f / (1.0f + __expf(-v)); }
static __device__ __forceinline__ float tanhfast(float v) {
    // 1 - 2/(e^{2v}+1); saturates correctly at +/-1 via expf overflow/underflow
    return 1.0f - 2.0f / (__expf(2.0f * v) + 1.0f);
}

// ---------------------------------------------------------------------------
// Stage A: h_neigh[n1][c] = max_{f<15} relu( log1p(x[nbr0[n1,f]]) @ W_pool^T + b_pool )
// Block: 4 groups (60 gathered rows) x 128 cols, K=128. 256 threads (240 compute).
// relu-then-max == max-then-relu (monotone), uint-punned LDS atomicMax (vals >= 0).
// ---------------------------------------------------------------------------
__global__ __launch_bounds__(256) void pool_max_kernel(
    const float* __restrict__ x, const int* __restrict__ nbr0,
    const float* __restrict__ Wp, const float* __restrict__ bp,
    float* __restrict__ h_neigh)
{
    __shared__ float a_t[60 * 132];      // full K=128, row stride 132 (conflict-free)
    __shared__ float w_t[128 * 36];      // 32-k chunk, c stride 36, k XOR-swizzled
    __shared__ unsigned red[4 * 128];

    const int tid = threadIdx.x;
    const size_t base_slot = (size_t)blockIdx.x * 60;

    // stage gathered A rows (60 x 128) with log1p applied
    for (int i = tid; i < 60 * 32; i += 256) {
        const int row = i >> 5, f4 = i & 31;
        const int node = nbr0[base_slot + row];
        float4 v = *(const float4*)(x + (size_t)node * 128 + f4 * 4);
        v.x = flog1p(v.x); v.y = flog1p(v.y); v.z = flog1p(v.z); v.w = flog1p(v.w);
        *(float4*)&a_t[row * 132 + f4 * 4] = v;
    }
    for (int i = tid; i < 512; i += 256) red[i] = 0u;

    const int tr = tid >> 4;   // 0..15 (tr==15 idle in compute)
    const int tc = tid & 15;
    const bool active = (tr < 15);

    float acc[4][8];
#pragma unroll
    for (int g = 0; g < 4; ++g)
#pragma unroll
        for (int j = 0; j < 8; ++j) acc[g][j] = 0.0f;

    for (int kc = 0; kc < 4; ++kc) {
        __syncthreads();
        for (int i = tid; i < 128 * 32; i += 256) {
            const int c = i >> 5, kk = i & 31;
            const int sw = ((c >> 3) & 7) << 2;
            w_t[c * 36 + (kk ^ sw)] = Wp[(size_t)c * 128 + kc * 32 + kk];
        }
        __syncthreads();
        if (active) {
#pragma unroll 2
            for (int k0 = 0; k0 < 32; k0 += 4) {
                float4 av[4];
#pragma unroll
                for (int g = 0; g < 4; ++g)
                    av[g] = *(const float4*)&a_t[(tr + 15 * g) * 132 + kc * 32 + k0];
#pragma unroll
                for (int j = 0; j < 8; ++j) {
                    const int c = tc * 8 + j;
                    const int sw = ((c >> 3) & 7) << 2;
                    const float4 wv = *(const float4*)&w_t[c * 36 + (k0 ^ sw)];
#pragma unroll
                    for (int g = 0; g < 4; ++g) {
                        acc[g][j] = fmaf(av[g].x, wv.x, acc[g][j]);
                        acc[g][j] = fmaf(av[g].y, wv.y, acc[g][j]);
                        acc[g][j] = fmaf(av[g].z, wv.z, acc[g][j]);
                        acc[g][j] = fmaf(av[g].w, wv.w, acc[g][j]);
                    }
                }
            }
        }
    }
    __syncthreads();
    if (active) {
#pragma unroll
        for (int j = 0; j < 8; ++j) {
            const int c = tc * 8 + j;
            const float b = bp[c];
#pragma unroll
            for (int g = 0; g < 4; ++g) {
                const float v = fmaxf(acc[g][j] + b, 0.0f);
                atomicMax(&red[g * 128 + c], __float_as_uint(v));
            }
        }
    }
    __syncthreads();
    for (int i = tid; i < 512; i += 256) {
        const int g = i >> 7, c = i & 127;
        h_neigh[((size_t)blockIdx.x * 4 + g) * 128 + c] = __uint_as_float(red[i]);
    }
}

// ---------------------------------------------------------------------------
// Stage B: h0 = [log1p(x[:N1]) | h_neigh] @ [W_self0 | W_neigh0]^T + b0  (pre-BN)
// + fused column sum/sumsq partials (LDS reduce, 1 atomicAdd per col per block).
// M=40960 (64/block), N=256 (128/block), K=256 (8 chunks of 32).
// ---------------------------------------------------------------------------
__global__ __launch_bounds__(256) void h0_kernel(
    const float* __restrict__ x, const float* __restrict__ hn,
    const float* __restrict__ Ws, const float* __restrict__ Wn,
    const float* __restrict__ bias0, float* __restrict__ h0,
    float* __restrict__ bn_sum, float* __restrict__ bn_sq)
{
    __shared__ float a_t[64 * 36];
    __shared__ float w_t[128 * 36];

    const int tid = threadIdx.x;
    const int m0 = blockIdx.x * 64;
    const int c0 = blockIdx.y * 128;
    const int tr = tid >> 4, tc = tid & 15;

    float acc[4][8];
#pragma unroll
    for (int i = 0; i < 4; ++i)
#pragma unroll
        for (int j = 0; j < 8; ++j) acc[i][j] = 0.0f;

    for (int kc = 0; kc < 8; ++kc) {
        __syncthreads();
        for (int i = tid; i < 64 * 32; i += 256) {
            const int row = i >> 5, kk = i & 31;
            float v;
            if (kc < 4) v = flog1p(x[(size_t)(m0 + row) * 128 + kc * 32 + kk]);
            else        v = hn[(size_t)(m0 + row) * 128 + (kc - 4) * 32 + kk];
            a_t[row * 36 + kk] = v;
        }
        for (int i = tid; i < 128 * 32; i += 256) {
            const int c = i >> 5, kk = i & 31;
            const int sw = ((c >> 3) & 7) << 2;
            const int cg = c0 + c;
            const float w = (kc < 4) ? Ws[(size_t)cg * 128 + kc * 32 + kk]
                                     : Wn[(size_t)cg * 128 + (kc - 4) * 32 + kk];
            w_t[c * 36 + (kk ^ sw)] = w;
        }
        __syncthreads();
#pragma unroll 2
        for (int k0 = 0; k0 < 32; k0 += 4) {
            float4 av[4];
#pragma unroll
            for (int i = 0; i < 4; ++i)
                av[i] = *(const float4*)&a_t[(tr * 4 + i) * 36 + k0];
#pragma unroll
            for (int j = 0; j < 8; ++j) {
                const int c = tc * 8 + j;
                const int sw = ((c >> 3) & 7) << 2;
                const float4 wv = *(const float4*)&w_t[c * 36 + (k0 ^ sw)];
#pragma unroll
                for (int i = 0; i < 4; ++i) {
                    acc[i][j] = fmaf(av[i].x, wv.x, acc[i][j]);
                    acc[i][j] = fmaf(av[i].y, wv.y, acc[i][j]);
                    acc[i][j] = fmaf(av[i].z, wv.z, acc[i][j]);
                    acc[i][j] = fmaf(av[i].w, wv.w, acc[i][j]);
                }
            }
        }
    }
    __syncthreads();

    float bb[8], s[8], q[8];
#pragma unroll
    for (int j = 0; j < 8; ++j) { bb[j] = bias0[c0 + tc * 8 + j]; s[j] = 0.0f; q[j] = 0.0f; }
#pragma unroll
    for (int i = 0; i < 4; ++i) {
        const size_t rg = (size_t)(m0 + tr * 4 + i);
        float v[8];
#pragma unroll
        for (int j = 0; j < 8; ++j) {
            v[j] = acc[i][j] + bb[j];
            s[j] += v[j];
            q[j] += v[j] * v[j];
        }
        float* p = h0 + rg * 256 + c0 + tc * 8;
        *(float4*)p       = make_float4(v[0], v[1], v[2], v[3]);
        *(float4*)(p + 4) = make_float4(v[4], v[5], v[6], v[7]);
    }
    float* redf = a_t;   // 2304 floats >= 2048 needed
#pragma unroll
    for (int j = 0; j < 8; ++j) redf[tr * 128 + tc * 8 + j] = s[j];
    __syncthreads();
    if (tid < 128) {
        float t = 0.0f;
#pragma unroll
        for (int r = 0; r < 16; ++r) t += redf[r * 128 + tid];
        atomicAdd(&bn_sum[c0 + tid], t);
    }
    __syncthreads();
#pragma unroll
    for (int j = 0; j < 8; ++j) redf[tr * 128 + tc * 8 + j] = q[j];
    __syncthreads();
    if (tid < 128) {
        float t = 0.0f;
#pragma unroll
        for (int r = 0; r < 16; ++r) t += redf[r * 128 + tid];
        atomicAdd(&bn_sq[c0 + tid], t);
    }
}

__global__ void bn_stats_kernel(const float* __restrict__ bn_sum, const float* __restrict__ bn_sq,
                                const float* __restrict__ gamma, const float* __restrict__ beta,
                                float* __restrict__ scale, float* __restrict__ shift)
{
    const int c = threadIdx.x;   // 256
    const float inv_n = 1.0f / (float)N1v;
    const float mu = bn_sum[c] * inv_n;
    const float var = bn_sq[c] * inv_n - mu * mu;
    const float rs = rsqrtf(var + 1e-5f);
    const float sc = rs * gamma[c];
    scale[c] = sc;
    shift[c] = beta[c] - mu * sc;
}

__global__ __launch_bounds__(256) void bn_apply_kernel(float* __restrict__ h0,
                                                       const float* __restrict__ scale,
                                                       const float* __restrict__ shift)
{
    const size_t i = (size_t)blockIdx.x * 256 + threadIdx.x;  // over N1*256/4 float4s
    float4 v = ((float4*)h0)[i];
    const int c = (int)((i * 4) & 255);
    v.x = fmaxf(fmaf(v.x, scale[c],     shift[c]),     0.0f);
    v.y = fmaxf(fmaf(v.y, scale[c + 1], shift[c + 1]), 0.0f);
    v.z = fmaxf(fmaf(v.z, scale[c + 2], shift[c + 2]), 0.0f);
    v.w = fmaxf(fmaf(v.w, scale[c + 3], shift[c + 3]), 0.0f);
    ((float4*)h0)[i] = v;
}

// ---------------------------------------------------------------------------
// Stage D1 (per step t): gbuf = [h0n[nbr1[:,t]] | h_prev] @ [W_ih | W_hh]^T + (b_ih+b_hh)
// M=4096 (64/block), N=1024 (128/block), K=512 (16 chunks of 32). t==0: h_prev = 0.
// ---------------------------------------------------------------------------
__global__ __launch_bounds__(256) void lstm_gates_kernel(
    const float* __restrict__ h0n, const int* __restrict__ nbr1,
    const float* __restrict__ hprev, const float* __restrict__ Wih,
    const float* __restrict__ Whh, const float* __restrict__ bih,
    const float* __restrict__ bhh, float* __restrict__ gbuf, int t)
{
    __shared__ float a_t[64 * 36];
    __shared__ float w_t[128 * 36];
    __shared__ int nodes[64];

    const int tid = threadIdx.x;
    const int m0 = blockIdx.x * 64;
    const int c0 = blockIdx.y * 128;
    const int tr = tid >> 4, tc = tid & 15;

    if (tid < 64) nodes[tid] = nbr1[(size_t)(m0 + tid) * 10 + t];

    float acc[4][8];
#pragma unroll
    for (int i = 0; i < 4; ++i)
#pragma unroll
        for (int j = 0; j < 8; ++j) acc[i][j] = 0.0f;

    for (int kc = 0; kc < 16; ++kc) {
        __syncthreads();
        for (int i = tid; i < 64 * 32; i += 256) {
            const int row = i >> 5, kk = i & 31;
            float v;
            if (kc < 8) v = h0n[(size_t)nodes[row] * 256 + kc * 32 + kk];
            else        v = (t == 0) ? 0.0f : hprev[(size_t)(m0 + row) * 256 + (kc - 8) * 32 + kk];
            a_t[row * 36 + kk] = v;
        }
        for (int i = tid; i < 128 * 32; i += 256) {
            const int c = i >> 5, kk = i & 31;
            const int sw = ((c >> 3) & 7) << 2;
            const int cg = c0 + c;
            const float w = (kc < 8) ? Wih[(size_t)cg * 256 + kc * 32 + kk]
                                     : Whh[(size_t)cg * 256 + (kc - 8) * 32 + kk];
            w_t[c * 36 + (kk ^ sw)] = w;
        }
        __syncthreads();
#pragma unroll 2
        for (int k0 = 0; k0 < 32; k0 += 4) {
            float4 av[4];
#pragma unroll
            for (int i = 0; i < 4; ++i)
                av[i] = *(const float4*)&a_t[(tr * 4 + i) * 36 + k0];
#pragma unroll
            for (int j = 0; j < 8; ++j) {
                const int c = tc * 8 + j;
                const int sw = ((c >> 3) & 7) << 2;
                const float4 wv = *(const float4*)&w_t[c * 36 + (k0 ^ sw)];
#pragma unroll
                for (int i = 0; i < 4; ++i) {
                    acc[i][j] = fmaf(av[i].x, wv.x, acc[i][j]);
                    acc[i][j] = fmaf(av[i].y, wv.y, acc[i][j]);
                    acc[i][j] = fmaf(av[i].z, wv.z, acc[i][j]);
                    acc[i][j] = fmaf(av[i].w, wv.w, acc[i][j]);
                }
            }
        }
    }

    float bb[8];
#pragma unroll
    for (int j = 0; j < 8; ++j) {
        const int cg = c0 + tc * 8 + j;
        bb[j] = bih[cg] + bhh[cg];
    }
#pragma unroll
    for (int i = 0; i < 4; ++i) {
        const size_t rg = (size_t)(m0 + tr * 4 + i);
        float v[8];
#pragma unroll
        for (int j = 0; j < 8; ++j) v[j] = acc[i][j] + bb[j];
        float* p = gbuf + rg * 1024 + c0 + tc * 8;
        *(float4*)p       = make_float4(v[0], v[1], v[2], v[3]);
        *(float4*)(p + 4) = make_float4(v[4], v[5], v[6], v[7]);
    }
}

// Stage D2 (per step t): LSTM pointwise. torch gate order i,f,g,o.
__global__ __launch_bounds__(256) void lstm_point_kernel(
    const float* __restrict__ gbuf, float* __restrict__ cst,
    float* __restrict__ hout, int t)
{
    const size_t gid = (size_t)blockIdx.x * 256 + threadIdx.x;  // < 4096*256
    const size_t b = gid >> 8;
    const int hh = (int)(gid & 255);
    const float gi = gbuf[b * 1024 + hh];
    const float gf = gbuf[b * 1024 + 256 + hh];
    const float gg = gbuf[b * 1024 + 512 + hh];
    const float go = gbuf[b * 1024 + 768 + hh];
    float c = sigf(gi) * tanhfast(gg);
    if (t > 0) c += sigf(gf) * cst[gid];
    const float h = sigf(go) * tanhfast(c);
    cst[gid] = c;
    hout[gid] = h;
}

// Stage E: out = h0n[:B] @ W_self1^T + hT @ W_neigh1^T + b1   [4096 x 32]
__global__ __launch_bounds__(256) void out_kernel(
    const float* __restrict__ h0n, const float* __restrict__ hT,
    const float* __restrict__ Ws, const float* __restrict__ Wn,
    const float* __restrict__ b1, float* __restrict__ out)
{
    const int gid = blockIdx.x * 256 + threadIdx.x;  // < 4096*32
    const int row = gid >> 5, c = gid & 31;
    const float4* a0 = (const float4*)(h0n + (size_t)row * 256);
    const float4* a1 = (const float4*)(hT + (size_t)row * 256);
    const float4* w0 = (const float4*)(Ws + (size_t)c * 256);
    const float4* w1 = (const float4*)(Wn + (size_t)c * 256);
    float s = b1[c];
#pragma unroll 4
    for (int k = 0; k < 64; ++k) {
        const float4 a = a0[k], w = w0[k];
        s += a.x * w.x + a.y * w.y + a.z * w.z + a.w * w.w;
    }
#pragma unroll 4
    for (int k = 0; k < 64; ++k) {
        const float4 a = a1[k], w = w1[k];
        s += a.x * w.x + a.y * w.y + a.z * w.z + a.w * w.w;
    }
    out[gid] = s;
}

extern "C" void kernel_launch(void* const* d_in, const int* in_sizes, int n_in,
                              void* d_out, int out_size, void* d_ws, size_t ws_size,
                              hipStream_t stream)
{
    const float* x        = (const float*)d_in[0];
    const int*   nbr0     = (const int*)d_in[1];
    const int*   nbr1     = (const int*)d_in[2];
    const float* W_pool   = (const float*)d_in[3];
    const float* b_pool   = (const float*)d_in[4];
    const float* W_self0  = (const float*)d_in[5];
    const float* W_neigh0 = (const float*)d_in[6];
    const float* b0       = (const float*)d_in[7];
    const float* gamma0   = (const float*)d_in[8];
    const float* beta0    = (const float*)d_in[9];
    const float* W_ih     = (const float*)d_in[10];
    const float* W_hh     = (const float*)d_in[11];
    const float* b_ih     = (const float*)d_in[12];
    const float* b_hh     = (const float*)d_in[13];
    const float* W_self1  = (const float*)d_in[14];
    const float* W_neigh1 = (const float*)d_in[15];
    const float* b1       = (const float*)d_in[16];
    float* out = (float*)d_out;

    // ws layout (floats). gbuf aliases h_neigh (dead after h0_kernel).
    // total = 5242880 + 10485760 + 1024 + 3*1048576 = 18,875,392 floats = 75.5 MB
    float* ws       = (float*)d_ws;
    float* h_neigh  = ws;                                   // N1*128
    float* gbuf     = ws;                                   // 4096*1024 (alias, later)
    float* h0       = ws + (size_t)N1v * 128;               // N1*256
    float* bn_sum   = h0 + (size_t)N1v * 256;               // 256
    float* bn_sq    = bn_sum + 256;                         // 256
    float* bn_scale = bn_sq + 256;                          // 256
    float* bn_shift = bn_scale + 256;                       // 256
    float* hs0      = bn_shift + 256;                       // 4096*256
    float* hs1      = hs0 + (size_t)BATCHv * 256;           // 4096*256
    float* cst      = hs1 + (size_t)BATCHv * 256;           // 4096*256

    hipMemsetAsync(bn_sum, 0, 512 * sizeof(float), stream);

    pool_max_kernel<<<N1v / 4, 256, 0, stream>>>(x, nbr0, W_pool, b_pool, h_neigh);
    h0_kernel<<<dim3(N1v / 64, 2), 256, 0, stream>>>(x, h_neigh, W_self0, W_neigh0,
                                                     b0, h0, bn_sum, bn_sq);
    bn_stats_kernel<<<1, 256, 0, stream>>>(bn_sum, bn_sq, gamma0, beta0, bn_scale, bn_shift);
    bn_apply_kernel<<<(N1v * 256 / 4) / 256, 256, 0, stream>>>(h0, bn_scale, bn_shift);

    for (int t = 0; t < 10; ++t) {
        const float* hp = (t & 1) ? hs1 : hs0;  // read (unused at t=0)
        float* hn       = (t & 1) ? hs0 : hs1;  // write
        lstm_gates_kernel<<<dim3(BATCHv / 64, 8), 256, 0, stream>>>(
            h0, nbr1, hp, W_ih, W_hh, b_ih, b_hh, gbuf, t);
        lstm_point_kernel<<<BATCHv, 256, 0, stream>>>(gbuf, cst, hn, t);
    }
    // after t=9 the final hidden state is in hs0
    out_kernel<<<(BATCHv * 32) / 256, 256, 0, stream>>>(h0, hs0, W_self1, W_neigh1, b1, out);
}

// Round 3
// 917.399 us; speedup vs baseline: 2.4858x; 2.4858x over previous
//
#include <hip/hip_runtime.h>

#define N0v 614400
#define N1v 40960
#define BATCHv 4096

typedef __attribute__((ext_vector_type(8))) short short8;
typedef __attribute__((ext_vector_type(4))) float floatx4;

static __device__ __forceinline__ float flog1p(float v) { return __logf(v + 1.0f); }
static __device__ __forceinline__ float sigf(float v) { return 1.0f / (1.0f + __expf(-v)); }
static __device__ __forceinline__ float tanhfast(float v) {
    return 1.0f - 2.0f / (__expf(2.0f * v) + 1.0f);
}
static __device__ __forceinline__ unsigned short f2bf(float f) {
    union { float f; unsigned u; } v; v.f = f;
    unsigned r = v.u + 0x7FFFu + ((v.u >> 16) & 1u);   // RNE
    return (unsigned short)(r >> 16);
}
static __device__ __forceinline__ float bf2f(unsigned short u) {
    return __uint_as_float(((unsigned)u) << 16);
}

// ---------------------------------------------------------------------------
// Weight pre-convert: fp32 -> bf16 copies in ws, plus bsum = b_ih + b_hh.
// Sizes: Wp 128x128=16384; Ws0/Wn0 256x128=32768; Wih/Whh 1024x256=262144;
// bsum 1024. Total 607232 elements -> grid 2372 x 256.
// ---------------------------------------------------------------------------
__global__ __launch_bounds__(256) void cvt_weights_kernel(
    const float* __restrict__ Wp, const float* __restrict__ Ws0,
    const float* __restrict__ Wn0, const float* __restrict__ Wih,
    const float* __restrict__ Whh, const float* __restrict__ bih,
    const float* __restrict__ bhh,
    unsigned short* __restrict__ Wpb, unsigned short* __restrict__ Ws0b,
    unsigned short* __restrict__ Wn0b, unsigned short* __restrict__ Wihb,
    unsigned short* __restrict__ Whhb, float* __restrict__ bsum)
{
    const int g = blockIdx.x * 256 + threadIdx.x;
    if (g < 16384)            Wpb[g] = f2bf(Wp[g]);
    else if (g < 49152)       Ws0b[g - 16384] = f2bf(Ws0[g - 16384]);
    else if (g < 81920)       Wn0b[g - 49152] = f2bf(Wn0[g - 49152]);
    else if (g < 344064)      Wihb[g - 81920] = f2bf(Wih[g - 81920]);
    else if (g < 606208)      Whhb[g - 344064] = f2bf(Whh[g - 344064]);
    else if (g < 607232) { const int i = g - 606208; bsum[i] = bih[i] + bhh[i]; }
}

// ---------------------------------------------------------------------------
// Stage A: pool-SAGE. Per block: 4 groups (60 gathered rows + 4 pad) x 128 cols,
// K=128 (2 staged chunks of 64). MFMA 16x16x32 bf16. relu+max epilogue via LDS
// atomicMax (uint-punned, vals >= 0). Output bf16.
// ---------------------------------------------------------------------------
__global__ __launch_bounds__(256) void pool_max_kernel(
    const float* __restrict__ x, const int* __restrict__ nbr0,
    const unsigned short* __restrict__ Wpb, const float* __restrict__ bp,
    unsigned short* __restrict__ hnb)
{
    __shared__ unsigned short smem[64 * 72 + 128 * 72];
    __shared__ unsigned red[512];
    __shared__ int nodes[64];
    unsigned short* aT = smem;
    unsigned short* wT = smem + 64 * 72;

    const int tid = threadIdx.x;
    const size_t base = (size_t)blockIdx.x * 60;
    if (tid < 64) nodes[tid] = (tid < 60) ? nbr0[base + tid] : 0;
    for (int i = tid; i < 512; i += 256) red[i] = 0u;

    const int lane = tid & 63, wv = tid >> 6;
    const int ml = lane & 15, q = lane >> 4, qk = q * 8;

    floatx4 acc[8];
#pragma unroll
    for (int ct = 0; ct < 8; ++ct) acc[ct] = (floatx4){0.f, 0.f, 0.f, 0.f};

    for (int kc = 0; kc < 2; ++kc) {
        __syncthreads();
        for (int i = tid; i < 512; i += 256) {            // A: 64 rows x 64 k
            const int row = i >> 3, seg = i & 7;
            short8 o = {0, 0, 0, 0, 0, 0, 0, 0};
            if (row < 60) {
                const float* s = x + (size_t)nodes[row] * 128 + kc * 64 + seg * 8;
                const float4 f0 = *(const float4*)s;
                const float4 f1 = *(const float4*)(s + 4);
                o[0] = (short)f2bf(flog1p(f0.x)); o[1] = (short)f2bf(flog1p(f0.y));
                o[2] = (short)f2bf(flog1p(f0.z)); o[3] = (short)f2bf(flog1p(f0.w));
                o[4] = (short)f2bf(flog1p(f1.x)); o[5] = (short)f2bf(flog1p(f1.y));
                o[6] = (short)f2bf(flog1p(f1.z)); o[7] = (short)f2bf(flog1p(f1.w));
            }
            *(short8*)&aT[row * 72 + seg * 8] = o;
        }
        for (int i = tid; i < 1024; i += 256) {           // W: 128 rows x 64 k
            const int row = i >> 3, seg = i & 7;
            *(short8*)&wT[row * 72 + seg * 8] =
                *(const short8*)&Wpb[(size_t)row * 128 + kc * 64 + seg * 8];
        }
        __syncthreads();
#pragma unroll
        for (int k0 = 0; k0 < 64; k0 += 32) {
            const short8 a = *(const short8*)&aT[(wv * 16 + ml) * 72 + k0 + qk];
#pragma unroll
            for (int ct = 0; ct < 8; ++ct) {
                const short8 b = *(const short8*)&wT[(ct * 16 + ml) * 72 + k0 + qk];
                acc[ct] = __builtin_amdgcn_mfma_f32_16x16x32_bf16(a, b, acc[ct], 0, 0, 0);
            }
        }
    }
    __syncthreads();
#pragma unroll
    for (int ct = 0; ct < 8; ++ct) {
        const int col = ct * 16 + ml;
        const float bb = bp[col];
#pragma unroll
        for (int r = 0; r < 4; ++r) {
            const int row = wv * 16 + q * 4 + r;
            if (row < 60) {
                const float v = fmaxf(acc[ct][r] + bb, 0.0f);
                atomicMax(&red[(row / 15) * 128 + col], __float_as_uint(v));
            }
        }
    }
    __syncthreads();
    for (int i = tid; i < 512; i += 256)
        hnb[(size_t)blockIdx.x * 512 + i] = f2bf(__uint_as_float(red[i]));
}

// ---------------------------------------------------------------------------
// Stage B: h0 = [log1p(x[:N1]) | h_neigh] @ [Ws0|Wn0]^T + b0, stored bf16 (pre-BN),
// with fused per-column sum/sumsq partials (LDS two-stage, 2 global atomics/col/blk).
// M=40960 (64/blk), N=256 (128/blk via gridDim.y=2), K=256 (4 chunks of 64).
// ---------------------------------------------------------------------------
__global__ __launch_bounds__(256) void h0_kernel(
    const float* __restrict__ x, const unsigned short* __restrict__ hnb,
    const unsigned short* __restrict__ Ws0b, const unsigned short* __restrict__ Wn0b,
    const float* __restrict__ b0, unsigned short* __restrict__ h0bf,
    float* __restrict__ bn_sum, float* __restrict__ bn_sq)
{
    __shared__ unsigned short smem[64 * 72 + 128 * 72];
    unsigned short* aT = smem;
    unsigned short* wT = smem + 64 * 72;

    const int tid = threadIdx.x;
    const int m0 = blockIdx.x * 64, c0 = blockIdx.y * 128;
    const int lane = tid & 63, wv = tid >> 6;
    const int ml = lane & 15, q = lane >> 4, qk = q * 8;

    floatx4 acc[8];
#pragma unroll
    for (int ct = 0; ct < 8; ++ct) acc[ct] = (floatx4){0.f, 0.f, 0.f, 0.f};

    for (int kc = 0; kc < 4; ++kc) {
        __syncthreads();
        for (int i = tid; i < 512; i += 256) {
            const int row = i >> 3, seg = i & 7;
            const int k = kc * 64 + seg * 8;
            if (kc < 2) {
                const float* s = x + (size_t)(m0 + row) * 128 + k;
                const float4 f0 = *(const float4*)s;
                const float4 f1 = *(const float4*)(s + 4);
                short8 o;
                o[0] = (short)f2bf(flog1p(f0.x)); o[1] = (short)f2bf(flog1p(f0.y));
                o[2] = (short)f2bf(flog1p(f0.z)); o[3] = (short)f2bf(flog1p(f0.w));
                o[4] = (short)f2bf(flog1p(f1.x)); o[5] = (short)f2bf(flog1p(f1.y));
                o[6] = (short)f2bf(flog1p(f1.z)); o[7] = (short)f2bf(flog1p(f1.w));
                *(short8*)&aT[row * 72 + seg * 8] = o;
            } else {
                *(short8*)&aT[row * 72 + seg * 8] =
                    *(const short8*)&hnb[(size_t)(m0 + row) * 128 + (k - 128)];
            }
        }
        for (int i = tid; i < 1024; i += 256) {
            const int row = i >> 3, seg = i & 7;
            const int k = kc * 64 + seg * 8;
            const size_t cg = (size_t)(c0 + row);
            *(short8*)&wT[row * 72 + seg * 8] = (kc < 2)
                ? *(const short8*)&Ws0b[cg * 128 + k]
                : *(const short8*)&Wn0b[cg * 128 + (k - 128)];
        }
        __syncthreads();
#pragma unroll
        for (int k0 = 0; k0 < 64; k0 += 32) {
            const short8 a = *(const short8*)&aT[(wv * 16 + ml) * 72 + k0 + qk];
#pragma unroll
            for (int ct = 0; ct < 8; ++ct) {
                const short8 b = *(const short8*)&wT[(ct * 16 + ml) * 72 + k0 + qk];
                acc[ct] = __builtin_amdgcn_mfma_f32_16x16x32_bf16(a, b, acc[ct], 0, 0, 0);
            }
        }
    }
    __syncthreads();
    float* scr = (float*)smem;   // 4096 floats = 16 KB <= 27.6 KB
#pragma unroll
    for (int ct = 0; ct < 8; ++ct) {
        const int col = ct * 16 + ml, cg = c0 + col;
        const float bb = b0[cg];
        float s = 0.f, sq = 0.f;
#pragma unroll
        for (int r = 0; r < 4; ++r) {
            const int row = wv * 16 + q * 4 + r;
            const float v = acc[ct][r] + bb;
            h0bf[(size_t)(m0 + row) * 256 + cg] = f2bf(v);
            s += v; sq += v * v;
        }
        scr[(wv * 4 + q) * 128 + col] = s;
        scr[2048 + (wv * 4 + q) * 128 + col] = sq;
    }
    __syncthreads();
    if (tid < 128) {
        float s = 0.f, sq = 0.f;
#pragma unroll
        for (int j = 0; j < 16; ++j) {
            s += scr[j * 128 + tid];
            sq += scr[2048 + j * 128 + tid];
        }
        atomicAdd(&bn_sum[c0 + tid], s);
        atomicAdd(&bn_sq[c0 + tid], sq);
    }
}

__global__ void bn_stats_kernel(const float* __restrict__ bn_sum, const float* __restrict__ bn_sq,
                                const float* __restrict__ gamma, const float* __restrict__ beta,
                                float* __restrict__ scale, float* __restrict__ shift)
{
    const int c = threadIdx.x;   // 256
    const float inv_n = 1.0f / (float)N1v;
    const float mu = bn_sum[c] * inv_n;
    const float var = bn_sq[c] * inv_n - mu * mu;
    const float rs = rsqrtf(var + 1e-5f);
    const float sc = rs * gamma[c];
    scale[c] = sc;
    shift[c] = beta[c] - mu * sc;
}

__global__ __launch_bounds__(256) void bn_apply_kernel(
    const unsigned short* __restrict__ h0bf, const float* __restrict__ scale,
    const float* __restrict__ shift, unsigned short* __restrict__ h0nbf)
{
    const int gid = blockIdx.x * 256 + threadIdx.x;   // over N1*256/8
    const int c0 = (gid * 8) & 255;
    const short8 v = *(const short8*)&h0bf[(size_t)gid * 8];
    short8 o;
#pragma unroll
    for (int j = 0; j < 8; ++j) {
        const float f = bf2f((unsigned short)v[j]);
        o[j] = (short)f2bf(fmaxf(fmaf(f, scale[c0 + j], shift[c0 + j]), 0.0f));
    }
    *(short8*)&h0nbf[(size_t)gid * 8] = o;
}

// ---------------------------------------------------------------------------
// LSTM gates (per step t): g = [h0n[nbr1[:,t]] | h_prev] @ [Wih|Whh]^T + bsum.
// Wih/Whh are each [1024 x 256]; concatenated along K -> K=512 (8 chunks of 64).
// M=4096 (64/blk), N=1024 (128/blk via gridDim.y=8).
// h_prev is a zeroed (disjoint) bf16 buffer at t=0.
// ---------------------------------------------------------------------------
__global__ __launch_bounds__(256) void lstm_gates_kernel(
    const unsigned short* __restrict__ h0nbf, const int* __restrict__ nbr1,
    const unsigned short* __restrict__ hbprev, const unsigned short* __restrict__ Wihb,
    const unsigned short* __restrict__ Whhb, const float* __restrict__ bsum,
    float* __restrict__ gbuf, int t)
{
    __shared__ unsigned short smem[64 * 72 + 128 * 72];
    __shared__ int nodes[64];
    unsigned short* aT = smem;
    unsigned short* wT = smem + 64 * 72;

    const int tid = threadIdx.x;
    const int m0 = blockIdx.x * 64, c0 = blockIdx.y * 128;
    const int lane = tid & 63, wv = tid >> 6;
    const int ml = lane & 15, q = lane >> 4, qk = q * 8;

    if (tid < 64) nodes[tid] = nbr1[(size_t)(m0 + tid) * 10 + t];

    floatx4 acc[8];
#pragma unroll
    for (int ct = 0; ct < 8; ++ct) acc[ct] = (floatx4){0.f, 0.f, 0.f, 0.f};

    for (int kc = 0; kc < 8; ++kc) {
        __syncthreads();
        for (int i = tid; i < 512; i += 256) {
            const int row = i >> 3, seg = i & 7;
            const int k = kc * 64 + seg * 8;
            *(short8*)&aT[row * 72 + seg * 8] = (kc < 4)
                ? *(const short8*)&h0nbf[(size_t)nodes[row] * 256 + k]
                : *(const short8*)&hbprev[(size_t)(m0 + row) * 256 + (k - 256)];
        }
        for (int i = tid; i < 1024; i += 256) {
            const int row = i >> 3, seg = i & 7;
            const int k = kc * 64 + seg * 8;
            const size_t cg = (size_t)(c0 + row);
            *(short8*)&wT[row * 72 + seg * 8] = (kc < 4)
                ? *(const short8*)&Wihb[cg * 256 + k]
                : *(const short8*)&Whhb[cg * 256 + (k - 256)];
        }
        __syncthreads();
#pragma unroll
        for (int k0 = 0; k0 < 64; k0 += 32) {
            const short8 a = *(const short8*)&aT[(wv * 16 + ml) * 72 + k0 + qk];
#pragma unroll
            for (int ct = 0; ct < 8; ++ct) {
                const short8 b = *(const short8*)&wT[(ct * 16 + ml) * 72 + k0 + qk];
                acc[ct] = __builtin_amdgcn_mfma_f32_16x16x32_bf16(a, b, acc[ct], 0, 0, 0);
            }
        }
    }
#pragma unroll
    for (int ct = 0; ct < 8; ++ct) {
        const int col = ct * 16 + ml;
        const float bb = bsum[c0 + col];
#pragma unroll
        for (int r = 0; r < 4; ++r) {
            const int row = wv * 16 + q * 4 + r;
            gbuf[(size_t)(m0 + row) * 1024 + c0 + col] = acc[ct][r] + bb;
        }
    }
}

// LSTM pointwise. torch gate order i,f,g,o. Writes c (fp32) and h (bf16).
__global__ __launch_bounds__(256) void lstm_point_kernel(
    const float* __restrict__ gbuf, float* __restrict__ cst,
    unsigned short* __restrict__ hb, int t)
{
    const int gid = blockIdx.x * 256 + threadIdx.x;   // < 4096*256
    const size_t b = (size_t)(gid >> 8);
    const int hh = gid & 255;
    const float gi = gbuf[b * 1024 + hh];
    const float gf = gbuf[b * 1024 + 256 + hh];
    const float gg = gbuf[b * 1024 + 512 + hh];
    const float go = gbuf[b * 1024 + 768 + hh];
    float c = sigf(gi) * tanhfast(gg);
    if (t > 0) c += sigf(gf) * cst[gid];
    cst[gid] = c;
    hb[gid] = f2bf(sigf(go) * tanhfast(c));
}

// Stage E: out = h0n[:B] @ W_self1^T + hT @ W_neigh1^T + b1   [4096 x 32]
__global__ __launch_bounds__(256) void out_kernel(
    const unsigned short* __restrict__ h0nbf, const unsigned short* __restrict__ hTb,
    const float* __restrict__ Ws1, const float* __restrict__ Wn1,
    const float* __restrict__ b1, float* __restrict__ out)
{
    const int gid = blockIdx.x * 256 + threadIdx.x;   // < 4096*32
    const int row = gid >> 5, c = gid & 31;
    const unsigned short* a0 = h0nbf + (size_t)row * 256;
    const unsigned short* a1 = hTb + (size_t)row * 256;
    const float* w0 = Ws1 + (size_t)c * 256;
    const float* w1 = Wn1 + (size_t)c * 256;
    float s = b1[c];
#pragma unroll 4
    for (int k8 = 0; k8 < 32; ++k8) {
        const short8 av = *(const short8*)&a0[k8 * 8];
        const short8 bv = *(const short8*)&a1[k8 * 8];
        const float4 wa0 = *(const float4*)&w0[k8 * 8];
        const float4 wa1 = *(const float4*)&w0[k8 * 8 + 4];
        const float4 wb0 = *(const float4*)&w1[k8 * 8];
        const float4 wb1 = *(const float4*)&w1[k8 * 8 + 4];
        s += bf2f((unsigned short)av[0]) * wa0.x + bf2f((unsigned short)av[1]) * wa0.y;
        s += bf2f((unsigned short)av[2]) * wa0.z + bf2f((unsigned short)av[3]) * wa0.w;
        s += bf2f((unsigned short)av[4]) * wa1.x + bf2f((unsigned short)av[5]) * wa1.y;
        s += bf2f((unsigned short)av[6]) * wa1.z + bf2f((unsigned short)av[7]) * wa1.w;
        s += bf2f((unsigned short)bv[0]) * wb0.x + bf2f((unsigned short)bv[1]) * wb0.y;
        s += bf2f((unsigned short)bv[2]) * wb0.z + bf2f((unsigned short)bv[3]) * wb0.w;
        s += bf2f((unsigned short)bv[4]) * wb1.x + bf2f((unsigned short)bv[5]) * wb1.y;
        s += bf2f((unsigned short)bv[6]) * wb1.z + bf2f((unsigned short)bv[7]) * wb1.w;
    }
    out[gid] = s;
}

extern "C" void kernel_launch(void* const* d_in, const int* in_sizes, int n_in,
                              void* d_out, int out_size, void* d_ws, size_t ws_size,
                              hipStream_t stream)
{
    const float* x        = (const float*)d_in[0];
    const int*   nbr0     = (const int*)d_in[1];
    const int*   nbr1     = (const int*)d_in[2];
    const float* W_pool   = (const float*)d_in[3];
    const float* b_pool   = (const float*)d_in[4];
    const float* W_self0  = (const float*)d_in[5];
    const float* W_neigh0 = (const float*)d_in[6];
    const float* b0       = (const float*)d_in[7];
    const float* gamma0   = (const float*)d_in[8];
    const float* beta0    = (const float*)d_in[9];
    const float* W_ih     = (const float*)d_in[10];
    const float* W_hh     = (const float*)d_in[11];
    const float* b_ih     = (const float*)d_in[12];
    const float* b_hh     = (const float*)d_in[13];
    const float* W_self1  = (const float*)d_in[14];
    const float* W_neigh1 = (const float*)d_in[15];
    const float* b1       = (const float*)d_in[16];
    float* out = (float*)d_out;

    // ws layout (bytes), fully disjoint except gbuf which aliases h0bf
    // (time-separated: h0bf dead after bn_apply, gbuf written from t=0).
    // Total 62.04 MB (R1 proved >= 75.5 MB available).
    char* ws = (char*)d_ws;
    unsigned short* h0bf  = (unsigned short*)(ws);               // 20,971,520 B
    float*          gbuf  = (float*)(ws);                        // 16,777,216 B (alias)
    unsigned short* hnb   = (unsigned short*)(ws + 20971520);    // 10,485,760 B
    unsigned short* h0nbf = (unsigned short*)(ws + 31457280);    // 20,971,520 B
    float*          cst   = (float*)(ws + 52428800);             //  4,194,304 B
    unsigned short* hb0   = (unsigned short*)(ws + 56623104);    //  2,097,152 B
    unsigned short* hb1   = (unsigned short*)(ws + 58720256);    //  2,097,152 B
    unsigned short* Wpb   = (unsigned short*)(ws + 60817408);    //     32,768 B
    unsigned short* Ws0b  = (unsigned short*)(ws + 60850176);    //     65,536 B
    unsigned short* Wn0b  = (unsigned short*)(ws + 60915712);    //     65,536 B
    unsigned short* Wihb  = (unsigned short*)(ws + 60981248);    //    524,288 B
    unsigned short* Whhb  = (unsigned short*)(ws + 61505536);    //    524,288 B
    float*          bsum  = (float*)(ws + 62029824);             //      4,096 B
    float*          bn_sum   = (float*)(ws + 62033920);
    float*          bn_sq    = (float*)(ws + 62034944);
    float*          bn_scale = (float*)(ws + 62035968);
    float*          bn_shift = (float*)(ws + 62036992);

    hipMemsetAsync(bn_sum, 0, 2048, stream);        // bn_sum + bn_sq
    hipMemsetAsync(hb0, 0, 2097152, stream);        // h_prev = 0 at t=0 (disjoint now)

    cvt_weights_kernel<<<2372, 256, 0, stream>>>(W_pool, W_self0, W_neigh0, W_ih, W_hh,
                                                 b_ih, b_hh, Wpb, Ws0b, Wn0b, Wihb, Whhb, bsum);
    pool_max_kernel<<<N1v / 4, 256, 0, stream>>>(x, nbr0, Wpb, b_pool, hnb);
    h0_kernel<<<dim3(N1v / 64, 2), 256, 0, stream>>>(x, hnb, Ws0b, Wn0b, b0,
                                                     h0bf, bn_sum, bn_sq);
    bn_stats_kernel<<<1, 256, 0, stream>>>(bn_sum, bn_sq, gamma0, beta0, bn_scale, bn_shift);
    bn_apply_kernel<<<(N1v * 256 / 8) / 256, 256, 0, stream>>>(h0bf, bn_scale, bn_shift, h0nbf);

    for (int t = 0; t < 10; ++t) {
        const unsigned short* hp = (t & 1) ? hb1 : hb0;
        unsigned short*       hn = (t & 1) ? hb0 : hb1;
        lstm_gates_kernel<<<dim3(BATCHv / 64, 8), 256, 0, stream>>>(
            h0nbf, nbr1, hp, Wihb, Whhb, bsum, gbuf, t);
        lstm_point_kernel<<<BATCHv * 256 / 256, 256, 0, stream>>>(gbuf, cst, hn, t);
    }
    // t=9 wrote hb0 -> final hidden state
    out_kernel<<<(BATCHv * 32) / 256, 256, 0, stream>>>(h0nbf, hb0, W_self1, W_neigh1, b1, out);
}